// Round 3
// baseline (159.959 us; speedup 1.0000x reference)
//
#include <hip/hip_runtime.h>

namespace {
constexpr int CIN = 64, COUT = 64, SS = 1024, KK = 3;
constexpr int STL = 4;            // s per block
constexpr int POS = STL + 2;      // 6 halo positions
constexpr int NCG = 8, CPG = 8;   // 8 c-groups of 8 channels (one wave each)
constexpr int WROW  = 20;         // LDS dwords per o-row: 4 sl * 4 (k padded to 4) + 4 pad
                                  //  -> b128-aligned reads at exact bank floor (starts {0,16}+{0,4,8,12})
constexpr int WSLAB = COUT * WROW;              // 1280 dwords per weight buffer
constexpr int WOFF  = CIN * POS * 16;           // 6144 dwords: input tile region
constexpr int SMEMDW = WOFF + NCG * 2 * WSLAB;  // 26624 dwords = 104 KB
}

// Block = 512 threads = 8 waves. Thread (sl 0..3, og 0..15 -> 4 o's, cg 0..7 -> 8 c's).
// Weight path: per-wave double-buffered LDS slab per channel, staged with float4
// loads (3/lane), 2-deep prefetch; consumed as 4x aligned ds_read_b128 per c.
// Slabs are wave-private -> no barriers in the c-loop (same-wave ds ordering suffices).
//
// R3 fix: amdgpu_waves_per_eu(2,2). R1/R2 showed VGPR_Count pinned at exactly 128
// (= 4 waves/EU budget) regardless of __launch_bounds__ 2nd arg, with ~106 MB of
// scratch WRITE traffic (acc spills) -- the allocator targets 4 waves/EU by its own
// heuristic even though LDS=104 KB caps the kernel at 1 block/CU = 2 waves/EU.
// Setting max waves/EU = 2 stops the occupancy-chasing and grants a 256-VGPR
// budget at zero real occupancy cost. Demand is ~150 -> no spill.
// CRITICAL (kept): every array index is compile-time (fully unrolled) -- runtime
// indexing demotes arrays to scratch.
__global__ __attribute__((amdgpu_waves_per_eu(2, 2))) __launch_bounds__(512)
void locon1d(const float* __restrict__ in, const float* __restrict__ wt,
             const float* __restrict__ bias, float* __restrict__ out) {
  __shared__ float smem[SMEMDW];

  const int tid  = threadIdx.x;
  const int sl   = tid & 3;
  const int og   = (tid >> 2) & 15;
  const int cg   = tid >> 6;          // wave id
  const int lane = tid & 63;
  const int bid  = blockIdx.x;
  // XCD swizzle: adjacent s-tiles -> same XCD L2
  const int st  = ((bid & 7) << 5) + (bid >> 3);
  const int s0  = st * STL;
  const int o0  = og * 4;
  const int cb  = cg * CPG;

  // ---- stage input tile to LDS: xs[c][p][b], 64c x 6pos x 16b (24 KB) ----
  #pragma unroll
  for (int i = 0; i < 3; ++i) {
    const int t  = tid + i * 512;        // 0..1535 = 64c * 6p * 4bq
    const int c  = t / 24;
    const int r  = t - c * 24;
    const int bq = r / 6;
    const int p  = r - bq * 6;
    const int sg = s0 - 1 + p;
    const bool v = (unsigned)sg < (unsigned)SS;
    const float* ip = in + ((size_t)(4 * bq) * CIN + c) * SS + sg;
    float4 x4;
    x4.x = v ? ip[0] : 0.f;
    x4.y = v ? ip[(size_t)1 * CIN * SS] : 0.f;
    x4.z = v ? ip[(size_t)2 * CIN * SS] : 0.f;
    x4.w = v ? ip[(size_t)3 * CIN * SS] : 0.f;
    *reinterpret_cast<float4*>(&smem[(c * POS + p) * 16 + 4 * bq]) = x4;
  }
  __syncthreads();

  // ---- per-lane weight staging constants (c-independent) ----
  // Wave slab per c: w[o=0..63][s0..s0+3][k] = 64 * 12 contiguous dwords; lane
  // handles 3 chunks of 4 dwords: idx = r*64+lane -> (o = idx/3, part = idx%3).
  // Global chunk start = o*196608 + c*3072 + s0*3 + part*4  (16B-aligned: s0*3 % 4 == 0).
  int wg[3];        // global dword offset minus c*3072
  int wd[3][4];     // LDS dword slots: o*WROW + (f/3)*4 + f%3, f = part*4+j
  #pragma unroll
  for (int r = 0; r < 3; ++r) {
    const int idx = r * 64 + lane;
    const int oR  = idx / 3;
    const int pR  = idx - oR * 3;
    wg[r] = oR * (CIN * SS * KK) + pR * 4 + s0 * KK;
    #pragma unroll
    for (int j = 0; j < 4; ++j) {
      const int f  = pR * 4 + j;
      const int fs = f / 3;
      wd[r][j] = oR * WROW + fs * 4 + (f - fs * 3);
    }
  }
  float* const wlds = &smem[WOFF + cg * (2 * WSLAB)];

  float acc[4][16];
  #pragma unroll
  for (int oo = 0; oo < 4; ++oo)
    #pragma unroll
    for (int b = 0; b < 16; ++b) acc[oo][b] = 0.f;

  float4 wA[3], wB[3];

  #define WLOAD(DST, C_) do {                                                  \
    _Pragma("unroll")                                                          \
    for (int r = 0; r < 3; ++r)                                                \
      DST[r] = *reinterpret_cast<const float4*>(wt + wg[r] + (C_) * (SS * KK));\
  } while (0)

  WLOAD(wA, cb + 0);
  WLOAD(wB, cb + 1);

  // One channel step: write staged regs -> LDS slab, prefetch c+2, read own
  // weights as 4x ds_read_b128, FMA against input tile. No __syncthreads():
  // slab is wave-private; compiler's lgkmcnt orders the same-wave write->read.
  #define WSTEP(WREG, CC) do {                                                 \
    float* const wb = wlds + ((CC) & 1) * WSLAB;                               \
    _Pragma("unroll")                                                          \
    for (int r = 0; r < 3; ++r) {                                              \
      wb[wd[r][0]] = WREG[r].x;                                                \
      wb[wd[r][1]] = WREG[r].y;                                                \
      wb[wd[r][2]] = WREG[r].z;                                                \
      wb[wd[r][3]] = WREG[r].w;                                                \
    }                                                                          \
    if ((CC) + 2 < CPG) WLOAD(WREG, cb + (CC) + 2);                            \
    float4 wq[4];                                                              \
    _Pragma("unroll")                                                          \
    for (int oo = 0; oo < 4; ++oo)                                             \
      wq[oo] = *reinterpret_cast<const float4*>(&wb[(o0 + oo) * WROW + sl * 4]);\
    const int c_ = cb + (CC);                                                  \
    _Pragma("unroll")                                                          \
    for (int k = 0; k < KK; ++k) {                                             \
      const float* base_ = &smem[(c_ * POS + sl + k) * 16];                    \
      _Pragma("unroll")                                                        \
      for (int g = 0; g < 4; ++g) {                                            \
        const float4 x4 = *reinterpret_cast<const float4*>(base_ + 4 * g);     \
        _Pragma("unroll")                                                      \
        for (int oo = 0; oo < 4; ++oo) {                                       \
          const float wv = (k == 0) ? wq[oo].x : (k == 1) ? wq[oo].y : wq[oo].z;\
          acc[oo][4 * g + 0] += wv * x4.x;                                     \
          acc[oo][4 * g + 1] += wv * x4.y;                                     \
          acc[oo][4 * g + 2] += wv * x4.z;                                     \
          acc[oo][4 * g + 3] += wv * x4.w;                                     \
        }                                                                      \
      }                                                                        \
    }                                                                          \
  } while (0)

  WSTEP(wA, 0); WSTEP(wB, 1);
  WSTEP(wA, 2); WSTEP(wB, 3);
  WSTEP(wA, 4); WSTEP(wB, 5);
  WSTEP(wA, 6); WSTEP(wB, 7);

  #undef WSTEP
  #undef WLOAD

  // ---- in-block reduction over cg (8 partials) + coalesced epilogue ----
  // (unchanged; first __syncthreads also guards xs/weight-slab aliasing)
  #pragma unroll
  for (int oo = 0; oo < 4; ++oo) {
    __syncthreads();
    #pragma unroll
    for (int b = 0; b < 16; ++b)
      smem[cg * 1024 + (b * 16 + og) * 4 + sl] = acc[oo][b];
    __syncthreads();
    #pragma unroll
    for (int i = 0; i < 2; ++i) {
      const int item = tid + i * 512;     // (b 0..15, og2 0..15, sl2 0..3)
      float sum = 0.f;
      #pragma unroll
      for (int g = 0; g < NCG; ++g) sum += smem[g * 1024 + item];
      const int b   = item >> 6;
      const int rem = item & 63;
      const int o   = (rem >> 2) * 4 + oo;
      const int s2  = s0 + (rem & 3);
      out[((size_t)b * COUT + o) * SS + s2] = sum + bias[o * SS + s2];
    }
  }
}

extern "C" void kernel_launch(void* const* d_in, const int* in_sizes, int n_in,
                              void* d_out, int out_size, void* d_ws, size_t ws_size,
                              hipStream_t stream) {
  const float* in = (const float*)d_in[0];
  const float* wt = (const float*)d_in[1];
  const float* bs = (const float*)d_in[2];
  float* out = (float*)d_out;
  // 256 s-tiles (4 s each), full o & c per block; 256 blocks x 8 waves
  hipLaunchKernelGGL(locon1d, dim3(256), dim3(512), 0, stream, in, wt, bs, out);
}

// Round 5
// 99.615 us; speedup vs baseline: 1.6058x; 1.6058x over previous
//
#include <hip/hip_runtime.h>

namespace {
constexpr int CIN = 64, COUT = 64, SS = 1024, KK = 3;
constexpr int STL = 4;            // s per block
constexpr int POS = STL + 2;      // 6 halo positions
constexpr int NCG = 8, CPG = 8;   // 8 c-groups of 8 channels (one wave each)
}

// Block = 512 threads = 8 waves. Thread (sl 0..3, og 0..15 -> 4 o's, cg 0..7 -> 8 c's).
// R4/R5: R0 skeleton (input staging / compute indexing / epilogue verbatim) with the
// weight path restructured as a 3-deep rotating register prefetch: 12 weights per
// channel (wA/wB/wC = 36 VGPRs), load channel c+3 while computing channel c.
//
// Why: R1-R3 showed the register allocator pins this kernel at 128 VGPRs no matter
// what (__launch_bounds__ 2nd arg and amdgpu_waves_per_eu(2,2) both ignored), and
// any design whose live set exceeds 128 spills acc to scratch (~106 MB of HBM
// write traffic, 84 us). R0 fit only because the compiler sank its 96 upfront
// weight loads to per-use -> zero prefetch distance, HBM latency exposed (~16 us
// vs ~10 us floor). This version's peak live set is ~112 VGPRs (acc 64 + 36
// prefetch + misc): fits the cap, no spill, ~2 channel-steps of latency cover.
// CRITICAL (kept): every array index is compile-time (fully unrolled) -- runtime
// indexing demotes arrays to scratch.
__global__ __launch_bounds__(512)
void locon1d(const float* __restrict__ in, const float* __restrict__ wt,
             const float* __restrict__ bias, float* __restrict__ out) {
  __shared__ float smem[8192];  // 32 KB: xs uses 6144 floats; reused as partial buffer

  const int tid = threadIdx.x;
  const int sl  = tid & 3;
  const int og  = (tid >> 2) & 15;
  const int cg  = tid >> 6;           // == wave id
  const int bid = blockIdx.x;
  // XCD swizzle: adjacent s-tiles are bid,bid+8 -> same XCD -> weight/output lines merge in L2
  const int st  = ((bid & 7) << 5) + (bid >> 3);
  const int s0  = st * STL;
  const int s   = s0 + sl;
  const int o0  = og * 4;
  const int cb  = cg * CPG;

  // ---- stage input tile to LDS: xs[c][p][b], 64c x 6pos x 16b (24 KB) ----
  #pragma unroll
  for (int i = 0; i < 3; ++i) {
    const int t  = tid + i * 512;        // 0..1535 = 64c * 6p * 4bq
    const int c  = t / 24;
    const int r  = t - c * 24;
    const int bq = r / 6;
    const int p  = r - bq * 6;
    const int sg = s0 - 1 + p;
    const bool v = (unsigned)sg < (unsigned)SS;
    const float* ip = in + ((size_t)(4 * bq) * CIN + c) * SS + sg;
    float4 x4;
    x4.x = v ? ip[0] : 0.f;
    x4.y = v ? ip[(size_t)1 * CIN * SS] : 0.f;
    x4.z = v ? ip[(size_t)2 * CIN * SS] : 0.f;
    x4.w = v ? ip[(size_t)3 * CIN * SS] : 0.f;
    *reinterpret_cast<float4*>(&smem[(c * POS + p) * 16 + 4 * bq]) = x4;
  }
  __syncthreads();

  // ---- weight path: per-thread base, 12 dwords per channel, 3-deep rotation ----
  // element (oo, c, k) at wbase[oo*CIN*SS*KK + c*SS*KK + k]; k-triples are
  // contiguous (12 B) -> compiler merges to dwordx3 per (oo,c).
  const float* wbase = wt + ((size_t)o0 * CIN + cb) * (SS * KK) + (size_t)s * KK;

  float acc[4][16];
  #pragma unroll
  for (int oo = 0; oo < 4; ++oo)
    #pragma unroll
    for (int b = 0; b < 16; ++b) acc[oo][b] = 0.f;

  float wA[4][3], wB[4][3], wC[4][3];

  #define WLD(DST, C_) do {                                                    \
    _Pragma("unroll")                                                          \
    for (int oo = 0; oo < 4; ++oo)                                             \
      _Pragma("unroll")                                                        \
      for (int k = 0; k < KK; ++k)                                             \
        DST[oo][k] = wbase[(size_t)oo * (CIN * SS * KK) +                      \
                           (size_t)(C_) * (SS * KK) + k];                      \
  } while (0)

  // compute channel cb+C_ against LDS input tile (R0 inner loop, weights from W)
  #define CMP(W, C_) do {                                                      \
    _Pragma("unroll")                                                          \
    for (int k = 0; k < KK; ++k) {                                             \
      const float* base_ = &smem[((cb + (C_)) * POS + sl + k) * 16];           \
      _Pragma("unroll")                                                        \
      for (int g = 0; g < 4; ++g) {                                            \
        const float4 x4 = *reinterpret_cast<const float4*>(base_ + 4 * g);     \
        _Pragma("unroll")                                                      \
        for (int oo = 0; oo < 4; ++oo) {                                       \
          const float wv = W[oo][k];                                           \
          acc[oo][4 * g + 0] += wv * x4.x;                                     \
          acc[oo][4 * g + 1] += wv * x4.y;                                     \
          acc[oo][4 * g + 2] += wv * x4.z;                                     \
          acc[oo][4 * g + 3] += wv * x4.w;                                     \
        }                                                                      \
      }                                                                        \
    }                                                                          \
  } while (0)

  WLD(wA, 0); WLD(wB, 1); WLD(wC, 2);   // prologue: 3 channels in flight
  CMP(wA, 0); WLD(wA, 3);
  CMP(wB, 1); WLD(wB, 4);
  CMP(wC, 2); WLD(wC, 5);
  CMP(wA, 3); WLD(wA, 6);
  CMP(wB, 4); WLD(wB, 7);
  CMP(wC, 5);
  CMP(wA, 6);
  CMP(wB, 7);

  #undef WLD
  #undef CMP

  // ---- in-block reduction over cg (8 partials) + coalesced epilogue ----
  // FULLY UNROLLED over oo: acc/bank indices stay compile-time -> registers.
  #pragma unroll
  for (int oo = 0; oo < 4; ++oo) {
    __syncthreads();                      // round 0: also guards xs-alias
    #pragma unroll
    for (int b = 0; b < 16; ++b)
      smem[cg * 1024 + (b * 16 + og) * 4 + sl] = acc[oo][b];
    __syncthreads();
    #pragma unroll
    for (int i = 0; i < 2; ++i) {
      const int item = tid + i * 512;     // (b 0..15, og2 0..15, sl2 0..3)
      float sum = 0.f;
      #pragma unroll
      for (int g = 0; g < NCG; ++g) sum += smem[g * 1024 + item];
      const int b   = item >> 6;
      const int rem = item & 63;
      const int o   = (rem >> 2) * 4 + oo;
      const int s2  = s0 + (rem & 3);
      out[((size_t)b * COUT + o) * SS + s2] = sum + bias[o * SS + s2];
    }
  }
}

extern "C" void kernel_launch(void* const* d_in, const int* in_sizes, int n_in,
                              void* d_out, int out_size, void* d_ws, size_t ws_size,
                              hipStream_t stream) {
  const float* in = (const float*)d_in[0];
  const float* wt = (const float*)d_in[1];
  const float* bs = (const float*)d_in[2];
  float* out = (float*)d_out;
  // 256 s-tiles (4 s each), full o & c per block; 256 blocks x 8 waves
  hipLaunchKernelGGL(locon1d, dim3(256), dim3(512), 0, stream, in, wt, bs, out);
}